// Round 1
// baseline (48.843 us; speedup 1.0000x reference)
//
#include <hip/hip_runtime.h>
#include <hip/hip_bf16.h>
#include <math.h>

#define DEMBED 512
#define NTOK (64 * 1024)

// ---- tiny kernel: compute positional embedding table [DEMBED] into ws ----
__global__ void pos_kernel(float* __restrict__ pos) {
    int i = threadIdx.x;                 // one block of DEMBED threads
    if (i < DEMBED) {
        float ep_idx = (float)((i / 2) * 2);               // even index duplicated
        float ep = 1.0f / powf(10000.0f, ep_idx / (float)DEMBED);
        float p = (float)i * ep;
        pos[i] = (i & 1) ? cosf(p) : sinf(p);
    }
}

// ---- hot kernel: out[tok][d] = table[x[tok]][d] + pos[d], float4-vectorized ----
__global__ void __launch_bounds__(256)
embed_kernel(const int* __restrict__ x,
             const float* __restrict__ table,
             const float* __restrict__ pos,
             float* __restrict__ out,
             int n4)                                        // total float4 elements
{
    const float4* __restrict__ t4 = (const float4*)table;
    const float4* __restrict__ p4 = (const float4*)pos;
    float4* __restrict__ o4 = (float4*)out;

    int stride = gridDim.x * blockDim.x;
    for (int gid = blockIdx.x * blockDim.x + threadIdx.x; gid < n4; gid += stride) {
        int tok = gid >> 7;              // DEMBED/4 = 128 float4 per token
        int d4  = gid & 127;
        int row = x[tok];                // broadcast within wave (same tok for 64+ lanes)
        float4 t = t4[(size_t)row * 128 + d4];
        float4 p = p4[d4];
        float4 r;
        r.x = t.x + p.x; r.y = t.y + p.y; r.z = t.z + p.z; r.w = t.w + p.w;
        o4[gid] = r;
    }
}

extern "C" void kernel_launch(void* const* d_in, const int* in_sizes, int n_in,
                              void* d_out, int out_size, void* d_ws, size_t ws_size,
                              hipStream_t stream) {
    const int*   x     = (const int*)d_in[0];      // [64,1024] token ids
    const float* table = (const float*)d_in[1];    // [32000,512]
    float*       out   = (float*)d_out;            // [64,1024,512]
    float*       pos   = (float*)d_ws;             // DEMBED floats of scratch

    pos_kernel<<<1, DEMBED, 0, stream>>>(pos);

    int n4 = NTOK * (DEMBED / 4);                  // 8,388,608 float4 stores
    int blocks = 2048;                             // 256 CUs x 8 blocks/CU, grid-stride
    embed_kernel<<<blocks, 256, 0, stream>>>(x, table, pos, out, n4);
}

// Round 2
// 48.386 us; speedup vs baseline: 1.0094x; 1.0094x over previous
//
#include <hip/hip_runtime.h>
#include <hip/hip_bf16.h>
#include <math.h>

#define DEMBED 512
#define NTOK   (64 * 1024)
#define TPB    256
#define BLOCKS 2048
#define STRIDE (BLOCKS * TPB)          // 524288 threads
#define N4     (NTOK * (DEMBED / 4))   // 8388608 float4 elements
#define ITERS  (N4 / STRIDE)           // exactly 16

typedef float f4 __attribute__((ext_vector_type(4)));

// out[tok][d] = table[x[tok]][d] + pos[d]
// d4 = thread's float4-column is loop-invariant (STRIDE % 128 == 0), so each
// thread computes its 4 positional values once and streams 16 tokens' chunks.
__global__ void __launch_bounds__(TPB)
embed_kernel(const int* __restrict__ x,
             const float* __restrict__ table,
             float* __restrict__ out)
{
    const int tid = blockIdx.x * TPB + threadIdx.x;
    const int d4  = tid & 127;                     // float4 column, fixed per thread

    // ---- inline positional embedding for this thread's 4 columns ----
    f4 p;
    const float kLog = logf(10000.0f) / (float)DEMBED;
#pragma unroll
    for (int j = 0; j < 4; ++j) {
        int   i      = d4 * 4 + j;
        float ep_idx = (float)(i & ~1);            // even index duplicated to odd
        float ep     = expf(-ep_idx * kLog);       // 10000^(-ep_idx/512)
        float ang    = (float)i * ep;
        p[j] = (i & 1) ? cosf(ang) : sinf(ang);
    }

    const f4* __restrict__ t4 = (const f4*)table;
    f4*       __restrict__ o4 = (f4*)out;

    // ---- fully unrolled: 16 independent gather chains in flight ----
#pragma unroll
    for (int it = 0; it < ITERS; ++it) {
        int gid = tid + it * STRIDE;
        int tok = gid >> 7;                        // 128 float4 per token
        int row = x[tok];                          // wave-uniform address (L1 broadcast)
        f4  t   = t4[(size_t)row * 128 + d4];
        f4  r   = t + p;
        __builtin_nontemporal_store(r, &o4[gid]);  // streaming store: keep table in cache
    }
}

extern "C" void kernel_launch(void* const* d_in, const int* in_sizes, int n_in,
                              void* d_out, int out_size, void* d_ws, size_t ws_size,
                              hipStream_t stream) {
    const int*   x     = (const int*)d_in[0];      // [64,1024] token ids
    const float* table = (const float*)d_in[1];    // [32000,512]
    float*       out   = (float*)d_out;            // [64,1024,512]

    embed_kernel<<<BLOCKS, TPB, 0, stream>>>(x, table, out);
}